// Round 1
// baseline (344.106 us; speedup 1.0000x reference)
//
#include <hip/hip_runtime.h>

#define D_MODEL 2048
#define T 4096
#define NBATCH 2
#define ROWS (NBATCH*T)   // 8192
#define NP 112            // padded proj cols: 0-63 Q(h*32+d), 64-95 K, 96-97 W, 98-111 zero pad

typedef __attribute__((ext_vector_type(4))) float f32x4;
typedef __attribute__((ext_vector_type(8))) short bf16x8;

__device__ __forceinline__ short bf16_rne(float f) {
  unsigned u = __builtin_bit_cast(unsigned, f);
  u += 0x7fff + ((u >> 16) & 1);   // round-to-nearest-even
  return (short)(u >> 16);
}
__device__ __forceinline__ float bf16_f(short s) {
  unsigned u = ((unsigned)(unsigned short)s) << 16;
  return __builtin_bit_cast(float, u);
}

// ---------------- Kernel A: P[8192][112] = x @ [wq|wk|ww], fp32 ----------------
#define BM 128
#define BK 64
#define KS 8
#define KRANGE (D_MODEL/KS)   // 256
#define XLD 68                // pad: 16B-aligned rows, banks spread (68 % 32 == 4)
#define WLD 68

__global__ __launch_bounds__(512, 4)
void proj_kernel(const float* __restrict__ x, const float* __restrict__ wq,
                 const float* __restrict__ wk, const float* __restrict__ ww,
                 float* __restrict__ P) {
  __shared__ float xs[BM][XLD];     // x tile [row][k]
  __shared__ float wts[NP][WLD];    // weight tile transposed [col][k]
  const int tid = threadIdx.x;
  const int m0 = blockIdx.x * BM;
  const int k0 = blockIdx.y * KRANGE;
  const int cg = tid & 15;          // 16 col groups: cols cg + 16*i
  const int rt = tid >> 4;          // 32 row threads: rows rt*4 + j
  const int srow = tid >> 2, sq = tid & 3;  // x staging map

  float acc[4][7];
  #pragma unroll
  for (int j = 0; j < 4; ++j)
    #pragma unroll
    for (int i = 0; i < 7; ++i) acc[j][i] = 0.f;

  for (int c = 0; c < KRANGE/BK; ++c) {
    const int kb = k0 + c*BK;
    __syncthreads();
    { // stage x: 128 rows x 64 k, 16 f32/thread, coalesced
      const float* src = x + (size_t)(m0 + srow)*D_MODEL + kb + sq*16;
      f32x4 v0 = *(const f32x4*)(src+0);
      f32x4 v1 = *(const f32x4*)(src+4);
      f32x4 v2 = *(const f32x4*)(src+8);
      f32x4 v3 = *(const f32x4*)(src+12);
      *(f32x4*)&xs[srow][sq*16+0]  = v0;
      *(f32x4*)&xs[srow][sq*16+4]  = v1;
      *(f32x4*)&xs[srow][sq*16+8]  = v2;
      *(f32x4*)&xs[srow][sq*16+12] = v3;
    }
    // stage weights transposed: wts[col][k]; reads coalesced along col
    #pragma unroll
    for (int it = 0; it < (BK*NP)/512; ++it) {
      int idx = it*512 + tid;
      int k  = idx / NP;
      int cc = idx - k*NP;
      float v;
      if (cc < 64)      v = wq[(size_t)(kb+k)*64 + cc];
      else if (cc < 96) v = wk[(size_t)(kb+k)*32 + (cc-64)];
      else if (cc < 98) v = ww[(size_t)(kb+k)*2  + (cc-96)];
      else              v = 0.f;
      wts[cc][k] = v;
    }
    __syncthreads();
    #pragma unroll 2
    for (int k4 = 0; k4 < BK/4; ++k4) {
      f32x4 xv[4], wv[7];
      #pragma unroll
      for (int j = 0; j < 4; ++j) xv[j] = *(const f32x4*)&xs[rt*4+j][k4*4];
      #pragma unroll
      for (int i = 0; i < 7; ++i) wv[i] = *(const f32x4*)&wts[cg+16*i][k4*4];
      #pragma unroll
      for (int j = 0; j < 4; ++j)
        #pragma unroll
        for (int i = 0; i < 7; ++i)
          #pragma unroll
          for (int kk = 0; kk < 4; ++kk)
            acc[j][i] = fmaf(xv[j][kk], wv[i][kk], acc[j][i]);
    }
  }
  #pragma unroll
  for (int j = 0; j < 4; ++j)
    #pragma unroll
    for (int i = 0; i < 7; ++i)
      atomicAdd(&P[(size_t)(m0 + rt*4 + j)*NP + cg + 16*i], acc[j][i]);
}

// ------- Kernel B: out[b,t,s] = sum_h W[t,h]*relu(Q[t,h,:].K[s,:]), MFMA -------
// 128x128 tile/block, 4 waves each 64x64, hi/lo bf16 3-term MFMA from fp32 P.

__global__ __launch_bounds__(256, 4)
void score_kernel(const float* __restrict__ P, float* __restrict__ out) {
  const int tid  = threadIdx.x;
  const int lane = tid & 63;
  const int wv   = tid >> 6;
  const int wt = wv >> 1, wsi = wv & 1;
  const int l15 = lane & 15, kg = lane >> 4;
  const int bz = blockIdx.z;
  const int t0 = blockIdx.y * 128 + wt*64;
  const int s0 = blockIdx.x * 128 + wsi*64;
  const size_t prow_t = (size_t)bz*T + t0;
  const size_t prow_s = (size_t)bz*T + s0;

  // B-frags: K rows (s). B-frag layout: col(N)=lane&15, k=(lane>>4)*8+j
  bf16x8 bh[4], bl[4];
  #pragma unroll
  for (int nt = 0; nt < 4; ++nt) {
    const float* src = P + (prow_s + nt*16 + l15)*NP + 64 + kg*8;
    f32x4 v0 = *(const f32x4*)src;
    f32x4 v1 = *(const f32x4*)(src+4);
    #pragma unroll
    for (int j = 0; j < 8; ++j) {
      float v = (j < 4) ? v0[j] : v1[j-4];
      short h = bf16_rne(v);
      bh[nt][j] = h;
      bl[nt][j] = bf16_rne(v - bf16_f(h));
    }
  }

  float* ob = out + (size_t)bz*T*T;
  for (int mt = 0; mt < 4; ++mt) {
    // A-frags: Q rows (t), per head. A-frag layout: row(M)=lane&15, k=(lane>>4)*8+j
    bf16x8 ah[2], al[2];
    #pragma unroll
    for (int h = 0; h < 2; ++h) {
      const float* src = P + (prow_t + mt*16 + l15)*NP + h*32 + kg*8;
      f32x4 v0 = *(const f32x4*)src;
      f32x4 v1 = *(const f32x4*)(src+4);
      #pragma unroll
      for (int j = 0; j < 8; ++j) {
        float v = (j < 4) ? v0[j] : v1[j-4];
        short hh = bf16_rne(v);
        ah[h][j] = hh;
        al[h][j] = bf16_rne(v - bf16_f(hh));
      }
    }
    // per-(t,h) weights matching C/D row = (lane>>4)*4 + j
    float w0[4], w1[4];
    #pragma unroll
    for (int j = 0; j < 4; ++j) {
      const float* wp = P + (prow_t + mt*16 + kg*4 + j)*NP + 96;
      w0[j] = wp[0];
      w1[j] = wp[1];
    }
    #pragma unroll
    for (int nt = 0; nt < 4; ++nt) {
      f32x4 a0 = {0.f,0.f,0.f,0.f}, a1 = {0.f,0.f,0.f,0.f};
      a0 = __builtin_amdgcn_mfma_f32_16x16x32_bf16(ah[0], bh[nt], a0, 0,0,0);
      a0 = __builtin_amdgcn_mfma_f32_16x16x32_bf16(ah[0], bl[nt], a0, 0,0,0);
      a0 = __builtin_amdgcn_mfma_f32_16x16x32_bf16(al[0], bh[nt], a0, 0,0,0);
      a1 = __builtin_amdgcn_mfma_f32_16x16x32_bf16(ah[1], bh[nt], a1, 0,0,0);
      a1 = __builtin_amdgcn_mfma_f32_16x16x32_bf16(ah[1], bl[nt], a1, 0,0,0);
      a1 = __builtin_amdgcn_mfma_f32_16x16x32_bf16(al[1], bh[nt], a1, 0,0,0);
      const int scol = s0 + nt*16 + l15;
      #pragma unroll
      for (int j = 0; j < 4; ++j) {
        float r0 = fmaxf(a0[j], 0.f);
        float r1 = fmaxf(a1[j], 0.f);
        float o  = fmaf(w0[j], r0, w1[j]*r1);
        __builtin_nontemporal_store(o, ob + (size_t)(t0 + mt*16 + kg*4 + j)*T + scol);
      }
    }
  }
}

extern "C" void kernel_launch(void* const* d_in, const int* in_sizes, int n_in,
                              void* d_out, int out_size, void* d_ws, size_t ws_size,
                              hipStream_t stream) {
  const float* x  = (const float*)d_in[0];
  const float* wq = (const float*)d_in[1];
  const float* wk = (const float*)d_in[2];
  const float* ww = (const float*)d_in[3];
  float* P   = (float*)d_ws;             // [8192][112] f32 = 3.5 MB
  float* out = (float*)d_out;            // [2][4096][4096] f32

  hipMemsetAsync(P, 0, (size_t)ROWS * NP * sizeof(float), stream);

  dim3 gA(ROWS/BM, KS);                  // 64 x 8 = 512 blocks
  proj_kernel<<<gA, 512, 0, stream>>>(x, wq, wk, ww, P);

  dim3 gB(T/128, T/128, NBATCH);         // 32 x 32 x 2 = 2048 blocks
  score_kernel<<<gB, 256, 0, stream>>>(P, out);
}

// Round 4
// 260.788 us; speedup vs baseline: 1.3195x; 1.3195x over previous
//
#include <hip/hip_runtime.h>

#define D_MODEL 2048
#define T 4096
#define NBATCH 2
#define ROWS (NBATCH*T)   // 8192

typedef __attribute__((ext_vector_type(4))) float f32x4;
typedef __attribute__((ext_vector_type(2))) float f32x2;
typedef __attribute__((ext_vector_type(4))) int   i32x4;
typedef __attribute__((ext_vector_type(8))) short bf16x8;

union FU { i32x4 i; bf16x8 b; };

__device__ __forceinline__ unsigned fbits(float v){ return __builtin_bit_cast(unsigned, v); }
__device__ __forceinline__ float bcastf(unsigned u){ return __builtin_bit_cast(float, u); }
// pack top-16 bits (bf16 truncation) of two floats: low short = a, high short = b
__device__ __forceinline__ int pack_hi(float a, float b) {
  return (int)__builtin_amdgcn_perm(fbits(b), fbits(a), 0x07060302u);
}
__device__ __forceinline__ float resid(float v) {  // exact residual after bf16-trunc
  return v - bcastf(fbits(v) & 0xFFFF0000u);
}
__device__ __forceinline__ void cvt_frag(f32x4 v0, f32x4 v1, bf16x8& h, bf16x8& l) {
  FU H, L;
  H.i[0]=pack_hi(v0[0],v0[1]); H.i[1]=pack_hi(v0[2],v0[3]);
  H.i[2]=pack_hi(v1[0],v1[1]); H.i[3]=pack_hi(v1[2],v1[3]);
  L.i[0]=pack_hi(resid(v0[0]),resid(v0[1])); L.i[1]=pack_hi(resid(v0[2]),resid(v0[3]));
  L.i[2]=pack_hi(resid(v1[0]),resid(v1[1])); L.i[3]=pack_hi(resid(v1[2]),resid(v1[3]));
  h = H.b; l = L.b;
}
__device__ __forceinline__ f32x4 mfma16(bf16x8 a, bf16x8 b, f32x4 c) {
  return __builtin_amdgcn_mfma_f32_16x16x32_bf16(a, b, c, 0, 0, 0);
}

// ---------- prep: pack W=[wq|wk|ww|0] (2048x112) into MFMA B-frag planes ----------
// chunk(ks,nt): 2048B = hi-plane[64 lanes][16B] then lo-plane[64][16B]
// element j of lane: W[ks*32 + (lane>>4)*8 + j][nt*16 + (lane&15)]
__global__ __launch_bounds__(256)
void wprep_kernel(const float* __restrict__ wq, const float* __restrict__ wk,
                  const float* __restrict__ ww, unsigned char* __restrict__ Wpk) {
  const int lane = threadIdx.x & 63;
  const int chunk = blockIdx.x * 4 + (threadIdx.x >> 6);   // 0..447
  const int ks = chunk / 7, nt = chunk % 7;
  const int col = nt*16 + (lane & 15);
  const int kb  = ks*32 + (lane >> 4)*8;
  float v[8];
  #pragma unroll
  for (int j = 0; j < 8; ++j) {
    int k = kb + j;
    float t;
    if      (col < 64) t = wq[(size_t)k*64 + col];
    else if (col < 96) t = wk[(size_t)k*32 + (col-64)];
    else if (col < 98) t = ww[(size_t)k*2  + (col-96)];
    else               t = 0.f;
    v[j] = t;
  }
  i32x4 hi = { pack_hi(v[0],v[1]), pack_hi(v[2],v[3]), pack_hi(v[4],v[5]), pack_hi(v[6],v[7]) };
  i32x4 lo = { pack_hi(resid(v[0]),resid(v[1])), pack_hi(resid(v[2]),resid(v[3])),
               pack_hi(resid(v[4]),resid(v[5])), pack_hi(resid(v[6]),resid(v[7])) };
  unsigned char* base = Wpk + ((size_t)chunk << 11) + lane*16;
  *(i32x4*)base          = hi;
  *(i32x4*)(base + 1024) = lo;
}

// ---------- proj: P = x @ W via 3-term hi/lo bf16 MFMA ----------
// Ppk row (384B): u16[0..95] = hi(P[row][0..95]); u16[96..191] = lo. Pw[row][2] fp32.
__global__ __launch_bounds__(512, 2)
void proj_kernel(const float* __restrict__ x, const unsigned char* __restrict__ Wpk,
                 unsigned short* __restrict__ Ppk, float* __restrict__ Pw) {
  const int tid = threadIdx.x, lane = tid & 63, wv = tid >> 6;
  const int l15 = lane & 15, kg = lane >> 4;
  const int mt = wv >> 2, wp = wv & 3;
  const int m0 = blockIdx.x * 32;
  const bool hasB = (wp < 3);
  const int ntA = wp, ntB = wp + 4;

  const float* xrow = x + (size_t)(m0 + mt*16 + l15) * D_MODEL + kg*8;
  f32x4 acc0 = {0,0,0,0}, acc1 = {0,0,0,0};

  #pragma unroll 4
  for (int ks = 0; ks < 64; ++ks) {
    f32x4 v0 = *(const f32x4*)(xrow + ks*32);
    f32x4 v1 = *(const f32x4*)(xrow + ks*32 + 4);
    bf16x8 ah, al; cvt_frag(v0, v1, ah, al);
    const unsigned char* cb = Wpk + (((size_t)ks*7 + ntA) << 11) + lane*16;
    FU bh, bl; bh.i = *(const i32x4*)cb; bl.i = *(const i32x4*)(cb + 1024);
    acc0 = mfma16(ah, bh.b, acc0);
    acc0 = mfma16(ah, bl.b, acc0);
    acc0 = mfma16(al, bh.b, acc0);
    if (hasB) {
      const unsigned char* cb2 = Wpk + (((size_t)ks*7 + ntB) << 11) + lane*16;
      FU bh2, bl2; bh2.i = *(const i32x4*)cb2; bl2.i = *(const i32x4*)(cb2 + 1024);
      acc1 = mfma16(ah, bh2.b, acc1);
      acc1 = mfma16(ah, bl2.b, acc1);
      acc1 = mfma16(al, bh2.b, acc1);
    }
  }
  // epilogue: C/D layout col=lane&15, row=(lane>>4)*4+j
  #pragma unroll
  for (int s = 0; s < 2; ++s) {
    if (s == 1 && !hasB) break;
    const int nt = (s == 0) ? ntA : ntB;
    f32x4 a = (s == 0) ? acc0 : acc1;
    #pragma unroll
    for (int j = 0; j < 4; ++j) {
      const int row = m0 + mt*16 + kg*4 + j;
      const float v = a[j];
      if (nt < 6) {
        const int c = nt*16 + l15;
        unsigned u = fbits(v);
        Ppk[(size_t)row*192 + c]      = (unsigned short)(u >> 16);
        Ppk[(size_t)row*192 + 96 + c] = (unsigned short)(fbits(resid(v)) >> 16);
      } else if (l15 < 2) {
        Pw[(size_t)row*2 + l15] = v;   // head-weight columns, exact fp32
      }
    }
  }
}

// ---------- score: out[b,t,s] = sum_h Pw[t,h]*relu(Q[t,h,:].K[s,:]) ----------
__global__ __launch_bounds__(256, 4)
void score_kernel(const unsigned char* __restrict__ Ppk, const float* __restrict__ Pw,
                  float* __restrict__ out) {
  __shared__ float cbuf[4][16][76];
  const int tid = threadIdx.x, lane = tid & 63, wv = tid >> 6;
  const int l15 = lane & 15, kg = lane >> 4;
  const int wt = wv >> 1, wsi = wv & 1;
  const int bz = blockIdx.z;
  const int t0 = blockIdx.y * 128 + wt*64;
  const int s0 = blockIdx.x * 128 + wsi*64;
  const size_t rbase = (size_t)bz * T;

  // B-frags (K side): hi at row*384+128+kg*16, lo +192
  bf16x8 bh[4], bl[4];
  #pragma unroll
  for (int nt = 0; nt < 4; ++nt) {
    const unsigned char* pb = Ppk + (rbase + s0 + nt*16 + l15)*384 + 128 + kg*16;
    FU h, l; h.i = *(const i32x4*)pb; l.i = *(const i32x4*)(pb + 192);
    bh[nt] = h.b; bl[nt] = l.b;
  }

  for (int mt = 0; mt < 4; ++mt) {
    bf16x8 ah[2], al[2];
    #pragma unroll
    for (int h = 0; h < 2; ++h) {
      const unsigned char* pa = Ppk + (rbase + t0 + mt*16 + l15)*384 + h*64 + kg*16;
      FU hh, ll; hh.i = *(const i32x4*)pa; ll.i = *(const i32x4*)(pa + 192);
      ah[h] = hh.b; al[h] = ll.b;
    }
    float w0[4], w1[4];
    #pragma unroll
    for (int j = 0; j < 4; ++j) {
      f32x2 w = *(const f32x2*)(Pw + (rbase + t0 + mt*16 + kg*4 + j)*2);
      w0[j] = w[0]; w1[j] = w[1];
    }
    #pragma unroll
    for (int nt = 0; nt < 4; ++nt) {
      f32x4 a0 = {0,0,0,0}, a1 = {0,0,0,0};
      a0 = mfma16(ah[0], bh[nt], a0);
      a0 = mfma16(ah[0], bl[nt], a0);
      a0 = mfma16(al[0], bh[nt], a0);
      a1 = mfma16(ah[1], bh[nt], a1);
      a1 = mfma16(ah[1], bl[nt], a1);
      a1 = mfma16(al[1], bh[nt], a1);
      #pragma unroll
      for (int j = 0; j < 4; ++j) {
        cbuf[wv][kg*4+j][nt*16 + l15] =
            fmaf(w0[j], fmaxf(a0[j], 0.f), w1[j] * fmaxf(a1[j], 0.f));
      }
    }
    __syncthreads();
    #pragma unroll
    for (int it = 0; it < 4; ++it) {
      const int r = it*4 + kg;
      f32x4 vv = *(const f32x4*)&cbuf[wv][r][l15*4];
      *(f32x4*)(out + (size_t)bz*T*T + (size_t)(t0 + mt*16 + r)*T + s0 + l15*4) = vv;
    }
    __syncthreads();
  }
}

extern "C" void kernel_launch(void* const* d_in, const int* in_sizes, int n_in,
                              void* d_out, int out_size, void* d_ws, size_t ws_size,
                              hipStream_t stream) {
  const float* x  = (const float*)d_in[0];
  const float* wq = (const float*)d_in[1];
  const float* wk = (const float*)d_in[2];
  const float* ww = (const float*)d_in[3];

  // Wpk (896 KB) lives at the head of d_out; it is consumed by proj_kernel
  // before score_kernel overwrites the whole output.
  unsigned char*  Wpk = (unsigned char*)d_out;
  unsigned short* Ppk = (unsigned short*)d_ws;                       // 3 MB
  float*          Pw  = (float*)((unsigned char*)d_ws + (size_t)ROWS*384); // 64 KB
  float*          out = (float*)d_out;

  wprep_kernel<<<dim3(112), 256, 0, stream>>>(wq, wk, ww, Wpk);
  proj_kernel<<<dim3(ROWS/32), 512, 0, stream>>>(x, Wpk, Ppk, Pw);
  score_kernel<<<dim3(T/128, T/128, NBATCH), 256, 0, stream>>>(
      (const unsigned char*)Ppk, Pw, out);
}

// Round 8
// 243.091 us; speedup vs baseline: 1.4155x; 1.0728x over previous
//
#include <hip/hip_runtime.h>

#define D_MODEL 2048
#define T 4096
#define NBATCH 2
#define ROWS (NBATCH*T)   // 8192

typedef __attribute__((ext_vector_type(4))) float f32x4;
typedef __attribute__((ext_vector_type(2))) float f32x2;
typedef __attribute__((ext_vector_type(4))) int   i32x4;
typedef __attribute__((ext_vector_type(8))) short bf16x8;

union FU { i32x4 i; bf16x8 b; };

__device__ __forceinline__ unsigned fbits(float v){ return __builtin_bit_cast(unsigned, v); }
__device__ __forceinline__ float bcastf(unsigned u){ return __builtin_bit_cast(float, u); }
// pack top-16 bits (bf16 truncation) of two floats: low short = a, high short = b
__device__ __forceinline__ int pack_hi(float a, float b) {
  return (int)__builtin_amdgcn_perm(fbits(b), fbits(a), 0x07060302u);
}
__device__ __forceinline__ float resid(float v) {  // exact residual after bf16-trunc
  return v - bcastf(fbits(v) & 0xFFFF0000u);
}
__device__ __forceinline__ void cvt_frag(f32x4 v0, f32x4 v1, bf16x8& h, bf16x8& l) {
  FU H, L;
  H.i[0]=pack_hi(v0[0],v0[1]); H.i[1]=pack_hi(v0[2],v0[3]);
  H.i[2]=pack_hi(v1[0],v1[1]); H.i[3]=pack_hi(v1[2],v1[3]);
  L.i[0]=pack_hi(resid(v0[0]),resid(v0[1])); L.i[1]=pack_hi(resid(v0[2]),resid(v0[3]));
  L.i[2]=pack_hi(resid(v1[0]),resid(v1[1])); L.i[3]=pack_hi(resid(v1[2]),resid(v1[3]));
  h = H.b; l = L.b;
}
__device__ __forceinline__ f32x4 mfma16(bf16x8 a, bf16x8 b, f32x4 c) {
  return __builtin_amdgcn_mfma_f32_16x16x32_bf16(a, b, c, 0, 0, 0);
}

// ---------- prep: pack W=[wq|wk|ww|0] (2048x112) into MFMA B-frag planes ----------
// chunk(ks,nt): 2048B = hi-plane[64 lanes][16B] then lo-plane[64][16B]
// element j of lane: W[ks*32 + (lane>>4)*8 + j][nt*16 + (lane&15)]
__global__ __launch_bounds__(256)
void wprep_kernel(const float* __restrict__ wq, const float* __restrict__ wk,
                  const float* __restrict__ ww, unsigned char* __restrict__ Wpk) {
  const int lane = threadIdx.x & 63;
  const int chunk = blockIdx.x * 4 + (threadIdx.x >> 6);   // 0..447
  const int ks = chunk / 7, nt = chunk % 7;
  const int col = nt*16 + (lane & 15);
  const int kb  = ks*32 + (lane >> 4)*8;
  float v[8];
  #pragma unroll
  for (int j = 0; j < 8; ++j) {
    int k = kb + j;
    float t;
    if      (col < 64) t = wq[(size_t)k*64 + col];
    else if (col < 96) t = wk[(size_t)k*32 + (col-64)];
    else if (col < 98) t = ww[(size_t)k*2  + (col-96)];
    else               t = 0.f;
    v[j] = t;
  }
  i32x4 hi = { pack_hi(v[0],v[1]), pack_hi(v[2],v[3]), pack_hi(v[4],v[5]), pack_hi(v[6],v[7]) };
  i32x4 lo = { pack_hi(resid(v[0]),resid(v[1])), pack_hi(resid(v[2]),resid(v[3])),
               pack_hi(resid(v[4]),resid(v[5])), pack_hi(resid(v[6]),resid(v[7])) };
  unsigned char* base = Wpk + ((size_t)chunk << 11) + lane*16;
  *(i32x4*)base          = hi;
  *(i32x4*)(base + 1024) = lo;
}

// ---------- proj: P = x @ W via 3-term hi/lo bf16 MFMA ----------
// 512 thr = 8 waves; block owns 32 rows. Wave: mt=wv>>2 (16-row half),
// wp=wv&3 -> nt {wp, wp+4} (wp==3: single). Per-lane DIRECT x loads (L1 absorbs
// intra-block redundancy); explicit 1-group-ahead register prefetch (8 ks/group,
// 16 f32x4 staging x2 ping-pong) to break round-4's latency serialization.
// Ppk row (384B): u16[0..95] = hi(P[row][0..95]); u16[96..191] = lo. Pw[row][2] fp32.
__global__ __launch_bounds__(512, 2)
void proj_kernel(const float* __restrict__ x, const unsigned char* __restrict__ Wpk,
                 unsigned short* __restrict__ Ppk, float* __restrict__ Pw) {
  const int tid = threadIdx.x, lane = tid & 63, wv = tid >> 6;
  const int l15 = lane & 15, kg = lane >> 4;
  const int mt = wv >> 2, wp = wv & 3;
  const int m0 = blockIdx.x * 32;
  const bool hasB = (wp < 3);
  const int ntA = wp, ntB = wp + 4;

  const float* xrow = x + (size_t)(m0 + mt*16 + l15) * D_MODEL + kg*8;
  f32x4 acc0 = {0,0,0,0}, acc1 = {0,0,0,0};

  f32x4 cur[16], nxt[16];
  #pragma unroll
  for (int i = 0; i < 16; ++i)
    cur[i] = *(const f32x4*)(xrow + (i >> 1)*32 + (i & 1)*4);

  #pragma unroll 1
  for (int g = 0; g < 8; ++g) {
    if (g < 7) {
      #pragma unroll
      for (int i = 0; i < 16; ++i)
        nxt[i] = *(const f32x4*)(xrow + (g+1)*256 + (i >> 1)*32 + (i & 1)*4);
    }
    #pragma unroll
    for (int q = 0; q < 8; ++q) {
      bf16x8 ah, al; cvt_frag(cur[2*q], cur[2*q+1], ah, al);
      const size_t ks = (size_t)(g*8 + q);
      const unsigned char* cb = Wpk + ((ks*7 + ntA) << 11) + lane*16;
      FU bh, bl; bh.i = *(const i32x4*)cb; bl.i = *(const i32x4*)(cb + 1024);
      acc0 = mfma16(ah, bh.b, acc0);
      acc0 = mfma16(ah, bl.b, acc0);
      acc0 = mfma16(al, bh.b, acc0);
      if (hasB) {
        const unsigned char* cb2 = Wpk + ((ks*7 + ntB) << 11) + lane*16;
        FU bh2, bl2; bh2.i = *(const i32x4*)cb2; bl2.i = *(const i32x4*)(cb2 + 1024);
        acc1 = mfma16(ah, bh2.b, acc1);
        acc1 = mfma16(ah, bl2.b, acc1);
        acc1 = mfma16(al, bh2.b, acc1);
      }
    }
    #pragma unroll
    for (int i = 0; i < 16; ++i) cur[i] = nxt[i];
  }

  // epilogue: C/D layout col=lane&15, row=(lane>>4)*4+j
  #pragma unroll
  for (int s = 0; s < 2; ++s) {
    if (s == 1 && !hasB) break;
    const int nt = (s == 0) ? ntA : ntB;
    f32x4 a = (s == 0) ? acc0 : acc1;
    #pragma unroll
    for (int j = 0; j < 4; ++j) {
      const int row = m0 + mt*16 + kg*4 + j;
      const float v = a[j];
      if (nt < 6) {
        const int c = nt*16 + l15;
        Ppk[(size_t)row*192 + c]      = (unsigned short)(fbits(v) >> 16);
        Ppk[(size_t)row*192 + 96 + c] = (unsigned short)(fbits(resid(v)) >> 16);
      } else if (l15 < 2) {
        Pw[(size_t)row*2 + l15] = v;   // head-weight columns, exact fp32
      }
    }
  }
}

// ---------- score: out[b,t,s] = sum_h Pw[t,h]*relu(Q[t,h,:].K[s,:]) ----------
// cbuf is WAVE-PRIVATE: no __syncthreads needed (in-order LDS ops within a wave).
__global__ __launch_bounds__(256, 4)
void score_kernel(const unsigned char* __restrict__ Ppk, const float* __restrict__ Pw,
                  float* __restrict__ out) {
  __shared__ float cbuf[4][16][76];
  const int tid = threadIdx.x, lane = tid & 63, wv = tid >> 6;
  const int l15 = lane & 15, kg = lane >> 4;
  const int wt = wv >> 1, wsi = wv & 1;
  const int bz = blockIdx.z;
  const int t0 = blockIdx.y * 128 + wt*64;
  const int s0 = blockIdx.x * 128 + wsi*64;
  const size_t rbase = (size_t)bz * T;

  // B-frags (K side): hi at row*384+128+kg*16, lo +192
  bf16x8 bh[4], bl[4];
  #pragma unroll
  for (int nt = 0; nt < 4; ++nt) {
    const unsigned char* pb = Ppk + (rbase + s0 + nt*16 + l15)*384 + 128 + kg*16;
    FU h, l; h.i = *(const i32x4*)pb; l.i = *(const i32x4*)(pb + 192);
    bh[nt] = h.b; bl[nt] = l.b;
  }

  for (int mt = 0; mt < 4; ++mt) {
    bf16x8 ah[2], al[2];
    #pragma unroll
    for (int h = 0; h < 2; ++h) {
      const unsigned char* pa = Ppk + (rbase + t0 + mt*16 + l15)*384 + h*64 + kg*16;
      FU hh, ll; hh.i = *(const i32x4*)pa; ll.i = *(const i32x4*)(pa + 192);
      ah[h] = hh.b; al[h] = ll.b;
    }
    float w0[4], w1[4];
    #pragma unroll
    for (int j = 0; j < 4; ++j) {
      f32x2 w = *(const f32x2*)(Pw + (rbase + t0 + mt*16 + kg*4 + j)*2);
      w0[j] = w[0]; w1[j] = w[1];
    }
    #pragma unroll
    for (int nt = 0; nt < 4; ++nt) {
      f32x4 a0 = {0,0,0,0}, a1 = {0,0,0,0};
      a0 = mfma16(ah[0], bh[nt], a0);
      a0 = mfma16(ah[0], bl[nt], a0);
      a0 = mfma16(al[0], bh[nt], a0);
      a1 = mfma16(ah[1], bh[nt], a1);
      a1 = mfma16(ah[1], bl[nt], a1);
      a1 = mfma16(al[1], bh[nt], a1);
      #pragma unroll
      for (int j = 0; j < 4; ++j) {
        cbuf[wv][kg*4+j][nt*16 + l15] =
            fmaf(w0[j], fmaxf(a0[j], 0.f), w1[j] * fmaxf(a1[j], 0.f));
      }
    }
    // wave-private transpose readback (lgkmcnt ordering only, no barrier)
    #pragma unroll
    for (int it = 0; it < 4; ++it) {
      const int r = it*4 + kg;
      f32x4 vv = *(const f32x4*)&cbuf[wv][r][l15*4];
      float* dst = out + (size_t)bz*T*T + (size_t)(t0 + mt*16 + r)*T + s0 + l15*4;
      __builtin_nontemporal_store(vv, (f32x4*)dst);
    }
  }
}

extern "C" void kernel_launch(void* const* d_in, const int* in_sizes, int n_in,
                              void* d_out, int out_size, void* d_ws, size_t ws_size,
                              hipStream_t stream) {
  const float* x  = (const float*)d_in[0];
  const float* wq = (const float*)d_in[1];
  const float* wk = (const float*)d_in[2];
  const float* ww = (const float*)d_in[3];

  // Wpk (896 KB) lives at the head of d_out; it is consumed by proj_kernel
  // before score_kernel overwrites the whole output.
  unsigned char*  Wpk = (unsigned char*)d_out;
  unsigned short* Ppk = (unsigned short*)d_ws;                       // 3 MB
  float*          Pw  = (float*)((unsigned char*)d_ws + (size_t)ROWS*384); // 64 KB
  float*          out = (float*)d_out;

  wprep_kernel<<<dim3(112), 256, 0, stream>>>(wq, wk, ww, Wpk);
  proj_kernel<<<dim3(ROWS/32), 512, 0, stream>>>(x, Wpk, Ppk, Pw);
  score_kernel<<<dim3(T/128, T/128, NBATCH), 256, 0, stream>>>(
      (const unsigned char*)Ppk, Pw, out);
}